// Round 4
// baseline (154.972 us; speedup 1.0000x reference)
//
#include <hip/hip_runtime.h>
#include <math.h>

#define HH 4096
#define OO 4096
#define MAXLEN 2048

__device__ inline float wave_sum(float v) {
#pragma unroll
    for (int off = 32; off; off >>= 1) v += __shfl_down(v, off, 64);
    return v;
}
__device__ inline float wave_max(float v) {
#pragma unroll
    for (int off = 32; off; off >>= 1) v = fmaxf(v, __shfl_down(v, off, 64));
    return v;
}

// y[r0..r0+R) = act(W[r,:]·x + b[r]); L = 4096, R rows/block share the x stream
template <int R, int ACT>
__global__ void k_gemv4k(const float* __restrict__ W, const float* __restrict__ x,
                         const float* __restrict__ b, float* __restrict__ y) {
    int r0 = blockIdx.x * R;
    int t = threadIdx.x;
    const float4* xv = (const float4*)x;
    float acc[R];
#pragma unroll
    for (int rr = 0; rr < R; ++rr) acc[rr] = 0.f;
#pragma unroll
    for (int j = 0; j < 4; ++j) {
        float4 v = xv[t + 256 * j];
#pragma unroll
        for (int rr = 0; rr < R; ++rr) {
            float4 w = ((const float4*)(W + (size_t)(r0 + rr) * HH))[t + 256 * j];
            acc[rr] = fmaf(w.x, v.x, acc[rr]);
            acc[rr] = fmaf(w.y, v.y, acc[rr]);
            acc[rr] = fmaf(w.z, v.z, acc[rr]);
            acc[rr] = fmaf(w.w, v.w, acc[rr]);
        }
    }
    __shared__ float red[R][4];
    int wid = t >> 6, lane = t & 63;
#pragma unroll
    for (int rr = 0; rr < R; ++rr) {
        float s = wave_sum(acc[rr]);
        if (lane == 0) red[rr][wid] = s;
    }
    __syncthreads();
    if (t < R) {
        float g = red[t][0] + red[t][1] + red[t][2] + red[t][3] + b[r0 + t];
        if (ACT) g = fmaxf(g, 0.f);
        y[r0 + t] = g;
    }
}

// y[r0..r0+R) = act(W[r,:]·[emb | x2] + b[r]); L = 8192, R rows/block
template <int R, int ACT>
__global__ void k_cat_gemv(const float* __restrict__ W, const float* __restrict__ emb_W,
                           const int* __restrict__ idx, const float* __restrict__ x2,
                           const float* __restrict__ b, float* __restrict__ y) {
    int r0 = blockIdx.x * R;
    int t = threadIdx.x;
    const float4* e4 = (const float4*)(emb_W + (size_t)idx[0] * HH);
    const float4* v4 = (const float4*)x2;
    float acc[R];
#pragma unroll
    for (int rr = 0; rr < R; ++rr) acc[rr] = 0.f;
#pragma unroll
    for (int j = 0; j < 4; ++j) {
        float4 v = e4[t + 256 * j];
#pragma unroll
        for (int rr = 0; rr < R; ++rr) {
            float4 w = ((const float4*)(W + (size_t)(r0 + rr) * 2 * HH))[t + 256 * j];
            acc[rr] = fmaf(w.x, v.x, acc[rr]);
            acc[rr] = fmaf(w.y, v.y, acc[rr]);
            acc[rr] = fmaf(w.z, v.z, acc[rr]);
            acc[rr] = fmaf(w.w, v.w, acc[rr]);
        }
    }
#pragma unroll
    for (int j = 0; j < 4; ++j) {
        float4 v = v4[t + 256 * j];
#pragma unroll
        for (int rr = 0; rr < R; ++rr) {
            float4 w = ((const float4*)(W + (size_t)(r0 + rr) * 2 * HH + HH))[t + 256 * j];
            acc[rr] = fmaf(w.x, v.x, acc[rr]);
            acc[rr] = fmaf(w.y, v.y, acc[rr]);
            acc[rr] = fmaf(w.z, v.z, acc[rr]);
            acc[rr] = fmaf(w.w, v.w, acc[rr]);
        }
    }
    __shared__ float red[R][4];
    int wid = t >> 6, lane = t & 63;
#pragma unroll
    for (int rr = 0; rr < R; ++rr) {
        float s = wave_sum(acc[rr]);
        if (lane == 0) red[rr][wid] = s;
    }
    __syncthreads();
    if (t < R) {
        float g = red[t][0] + red[t][1] + red[t][2] + red[t][3] + b[r0 + t];
        if (ACT) g = fmaxf(g, 0.f);
        y[r0 + t] = g;
    }
}

// fused softmax + weighted partial column-sums.
// 512 blocks = 128 row-chunks (16 rows) x 4 col-quarters. Each block
// redundantly computes softmax stats from attlog (8KB, L2-resident).
// q==0 blocks also write atw (the third output).
__global__ void k_smpart(const float* __restrict__ attlog, const float* __restrict__ E,
                         float* __restrict__ part, float* __restrict__ atw) {
    __shared__ float red[4];
    __shared__ float s_mx, s_sum;
    int t = threadIdx.x;
    int q = blockIdx.x & 3;
    int c = blockIdx.x >> 2;              // 0..127

    float v[8];
    float m = -INFINITY;
#pragma unroll
    for (int j = 0; j < 8; ++j) { v[j] = attlog[t + 256 * j]; m = fmaxf(m, v[j]); }
    m = wave_max(m);
    if ((t & 63) == 0) red[t >> 6] = m;
    __syncthreads();
    if (t == 0) s_mx = fmaxf(fmaxf(red[0], red[1]), fmaxf(red[2], red[3]));
    __syncthreads();
    float mx = s_mx;
    float s = 0.f;
#pragma unroll
    for (int j = 0; j < 8; ++j) s += expf(v[j] - mx);
    s = wave_sum(s);
    __syncthreads();
    if ((t & 63) == 0) red[t >> 6] = s;
    __syncthreads();
    if (t == 0) s_sum = red[0] + red[1] + red[2] + red[3];
    __syncthreads();
    float inv = 1.0f / s_sum;

    int col4 = q * 256 + t;
    float4 acc = {0.f, 0.f, 0.f, 0.f};
#pragma unroll 8
    for (int rr = 0; rr < 16; ++rr) {
        int mrow = c * 16 + rr;
        float wm = expf(attlog[mrow] - mx) * inv;
        float4 e = ((const float4*)(E + (size_t)mrow * HH))[col4];
        acc.x = fmaf(wm, e.x, acc.x);
        acc.y = fmaf(wm, e.y, acc.y);
        acc.z = fmaf(wm, e.z, acc.z);
        acc.w = fmaf(wm, e.w, acc.w);
    }
    ((float4*)(part + (size_t)c * HH))[col4] = acc;

    if (q == 0 && t < 16) {
        int mrow = c * 16 + t;
        atw[mrow] = expf(attlog[mrow] - mx) * inv;
    }
}

// deterministic reduce of 128 partial rows -> atap
__global__ void k_red(const float* __restrict__ part, float* __restrict__ atap) {
    int j = blockIdx.x * 256 + threadIdx.x;
    float s = 0.f;
#pragma unroll 8
    for (int c = 0; c < 128; ++c) s += part[(size_t)c * HH + j];
    atap[j] = s;
}

// fused GRU: block r computes all 6 row-dots with shared x/h load streams,
// then gate math -> h_new[r]. 96KB of weights streamed per block.
__global__ void k_gru(const float* __restrict__ W_ih, const float* __restrict__ b_ih,
                      const float* __restrict__ W_hh, const float* __restrict__ b_hh,
                      const float* __restrict__ x, const float* __restrict__ h,
                      float* __restrict__ h_new) {
    __shared__ float red[6][4];
    int r = blockIdx.x;
    int t = threadIdx.x, wid = t >> 6, lane = t & 63;
    const float4* xv = (const float4*)x;
    const float4* hv = (const float4*)h;
    float acc[6] = {0.f, 0.f, 0.f, 0.f, 0.f, 0.f};
#pragma unroll
    for (int j = 0; j < 4; ++j) {
        float4 v = xv[t + 256 * j];
        float4 u = hv[t + 256 * j];
#pragma unroll
        for (int g = 0; g < 3; ++g) {
            float4 wi = ((const float4*)(W_ih + (size_t)(g * HH + r) * HH))[t + 256 * j];
            acc[g] = fmaf(wi.x, v.x, acc[g]);
            acc[g] = fmaf(wi.y, v.y, acc[g]);
            acc[g] = fmaf(wi.z, v.z, acc[g]);
            acc[g] = fmaf(wi.w, v.w, acc[g]);
            float4 wh = ((const float4*)(W_hh + (size_t)(g * HH + r) * HH))[t + 256 * j];
            acc[3 + g] = fmaf(wh.x, u.x, acc[3 + g]);
            acc[3 + g] = fmaf(wh.y, u.y, acc[3 + g]);
            acc[3 + g] = fmaf(wh.z, u.z, acc[3 + g]);
            acc[3 + g] = fmaf(wh.w, u.w, acc[3 + g]);
        }
    }
#pragma unroll
    for (int k = 0; k < 6; ++k) {
        float s = wave_sum(acc[k]);
        if (lane == 0) red[k][wid] = s;
    }
    __syncthreads();
    if (t == 0) {
        float g[6];
#pragma unroll
        for (int k = 0; k < 6; ++k) g[k] = red[k][0] + red[k][1] + red[k][2] + red[k][3];
        float i_r = g[0] + b_ih[r];
        float i_z = g[1] + b_ih[HH + r];
        float i_n = g[2] + b_ih[2 * HH + r];
        float h_r = g[3] + b_hh[r];
        float h_z = g[4] + b_hh[HH + r];
        float h_n = g[5] + b_hh[2 * HH + r];
        float rg = 1.f / (1.f + expf(-(i_r + h_r)));
        float z  = 1.f / (1.f + expf(-(i_z + h_z)));
        float n  = tanhf(i_n + rg * h_n);
        h_new[r] = (1.f - z) * n + z * h[r];
    }
}

// log_softmax over 4096, one block of 256 threads
__global__ void k_logsoftmax4096(const float* __restrict__ l, float* __restrict__ out) {
    __shared__ float red[4];
    __shared__ float bval;
    int t = threadIdx.x;
    float v[16];
    float m = -INFINITY;
#pragma unroll
    for (int j = 0; j < 16; ++j) { v[j] = l[t + 256 * j]; m = fmaxf(m, v[j]); }
    m = wave_max(m);
    if ((t & 63) == 0) red[t >> 6] = m;
    __syncthreads();
    if (t == 0) bval = fmaxf(fmaxf(red[0], red[1]), fmaxf(red[2], red[3]));
    __syncthreads();
    float mx = bval;
    float s = 0.f;
#pragma unroll
    for (int j = 0; j < 16; ++j) s += expf(v[j] - mx);
    s = wave_sum(s);
    __syncthreads();
    if ((t & 63) == 0) red[t >> 6] = s;
    __syncthreads();
    if (t == 0) bval = red[0] + red[1] + red[2] + red[3];
    __syncthreads();
    float lse = mx + logf(bval);
#pragma unroll
    for (int j = 0; j < 16; ++j) out[t + 256 * j] = v[j] - lse;
}

extern "C" void kernel_launch(void* const* d_in, const int* in_sizes, int n_in,
                              void* d_out, int out_size, void* d_ws, size_t ws_size,
                              hipStream_t stream) {
    const int*   idx     = (const int*)  d_in[0];
    const float* hidden  = (const float*)d_in[1];
    // d_in[2] (encoder_output) unused by the forward pass
    const float* enc     = (const float*)d_in[3];
    const float* emb_W   = (const float*)d_in[4];
    const float* att_W   = (const float*)d_in[5];
    const float* att_b   = (const float*)d_in[6];
    const float* atc_W   = (const float*)d_in[7];
    const float* atc_b   = (const float*)d_in[8];
    const float* W_ih    = (const float*)d_in[9];
    const float* W_hh    = (const float*)d_in[10];
    const float* b_ih    = (const float*)d_in[11];
    const float* b_hh    = (const float*)d_in[12];
    const float* out_W   = (const float*)d_in[13];
    const float* out_b   = (const float*)d_in[14];

    float* out    = (float*)d_out;        // [0, 4096)    log_softmax
    float* h_new  = out + OO;             // [4096, 8192) new hidden
    float* atw    = out + OO + HH;        // [8192,10240) attention weights

    float* ws         = (float*)d_ws;
    float* attlog     = ws;               // 2048
    float* atap       = ws + 2048;        // 4096
    float* x          = ws + 6144;        // 4096
    float* outlog     = ws + 10240;       // 4096
    float* part       = ws + 14336;       // 128*4096

    // 1. att logits: 1024 blocks x 2 rows
    k_cat_gemv<2, 0><<<MAXLEN / 2, 256, 0, stream>>>(att_W, emb_W, idx, hidden, att_b, attlog);
    // 2. fused softmax + weighted partial column-sums (also writes atw output)
    k_smpart<<<512, 256, 0, stream>>>(attlog, enc, part, atw);
    // 3. deterministic reduce -> atap
    k_red<<<16, 256, 0, stream>>>(part, atap);
    // 4. x = relu(atc_W @ [emb|atap] + atc_b): 2048 blocks x 2 rows
    k_cat_gemv<2, 1><<<HH / 2, 256, 0, stream>>>(atc_W, emb_W, idx, atap, atc_b, x);
    // 5. fused GRU -> h_new output
    k_gru<<<HH, 256, 0, stream>>>(W_ih, b_ih, W_hh, b_hh, x, hidden, h_new);
    // 6. out logits: 1024 blocks x 4 rows
    k_gemv4k<4, 0><<<HH / 4, 256, 0, stream>>>(out_W, h_new, out_b, outlog);
    // 7. log_softmax -> out (first output)
    k_logsoftmax4096<<<1, 256, 0, stream>>>(outlog, out);
}

// Round 5
// 130.069 us; speedup vs baseline: 1.1915x; 1.1915x over previous
//
#include <hip/hip_runtime.h>
#include <math.h>

#define HH 4096
#define OO 4096
#define MAXLEN 2048

typedef float f4 __attribute__((ext_vector_type(4)));

__device__ inline float wave_sum(float v) {
#pragma unroll
    for (int off = 32; off; off >>= 1) v += __shfl_down(v, off, 64);
    return v;
}
__device__ inline float wave_max(float v) {
#pragma unroll
    for (int off = 32; off; off >>= 1) v = fmaxf(v, __shfl_down(v, off, 64));
    return v;
}

// sum 256 per-thread partials; result valid in all threads
__device__ inline float block_sum(float acc) {
    __shared__ float red[4];
    acc = wave_sum(acc);
    int t = threadIdx.x;
    if ((t & 63) == 0) red[t >> 6] = acc;
    __syncthreads();
    return red[0] + red[1] + red[2] + red[3];
}

// per-thread partial dot over 1024*NV floats; 256 threads/block.
// NT: non-temporal (stream-once) hint on the W side only.
template <int NV, bool NT>
__device__ inline float dot_row(const f4* __restrict__ W4, const f4* __restrict__ x4) {
    int t = threadIdx.x;
    float acc = 0.f;
#pragma unroll
    for (int j = 0; j < NV; ++j) {
        f4 w = NT ? __builtin_nontemporal_load(W4 + t + 256 * j) : W4[t + 256 * j];
        f4 v = x4[t + 256 * j];
        acc = fmaf(w[0], v[0], acc);
        acc = fmaf(w[1], v[1], acc);
        acc = fmaf(w[2], v[2], acc);
        acc = fmaf(w[3], v[3], acc);
    }
    return acc;
}

// attention logits: block per row, L=8192 over [emb | hidden]; att_W stream-once
__global__ void k_att(const float* __restrict__ att_W, const float* __restrict__ att_b,
                      const float* __restrict__ emb_W, const int* __restrict__ idx,
                      const float* __restrict__ hidden, float* __restrict__ attlog) {
    int r = blockIdx.x;
    const float* emb = emb_W + (size_t)idx[0] * HH;
    const float* Wr = att_W + (size_t)r * (2 * HH);
    float acc = dot_row<4, true>((const f4*)Wr, (const f4*)emb)
              + dot_row<4, true>((const f4*)(Wr + HH), (const f4*)hidden);
    float tot = block_sum(acc);
    if (threadIdx.x == 0) attlog[r] = tot + att_b[r];
}

// fused softmax + weighted partial column-sums.
// 512 blocks = 128 row-chunks (16 rows) x 4 col-quarters. Each block
// redundantly computes softmax stats from attlog (8KB, L2/L3-resident).
// q==0 blocks also write atw (the third output). enc is stream-once (nt).
__global__ void k_smpart(const float* __restrict__ attlog, const float* __restrict__ E,
                         float* __restrict__ part, float* __restrict__ atw) {
    __shared__ float red[4];
    __shared__ float s_mx, s_sum;
    int t = threadIdx.x;
    int q = blockIdx.x & 3;
    int c = blockIdx.x >> 2;              // 0..127

    float v[8];
    float m = -INFINITY;
#pragma unroll
    for (int j = 0; j < 8; ++j) { v[j] = attlog[t + 256 * j]; m = fmaxf(m, v[j]); }
    m = wave_max(m);
    if ((t & 63) == 0) red[t >> 6] = m;
    __syncthreads();
    if (t == 0) s_mx = fmaxf(fmaxf(red[0], red[1]), fmaxf(red[2], red[3]));
    __syncthreads();
    float mx = s_mx;
    float s = 0.f;
#pragma unroll
    for (int j = 0; j < 8; ++j) s += expf(v[j] - mx);
    s = wave_sum(s);
    __syncthreads();
    if ((t & 63) == 0) red[t >> 6] = s;
    __syncthreads();
    if (t == 0) s_sum = red[0] + red[1] + red[2] + red[3];
    __syncthreads();
    float inv = 1.0f / s_sum;

    int col4 = q * 256 + t;
    f4 acc = {0.f, 0.f, 0.f, 0.f};
#pragma unroll 8
    for (int rr = 0; rr < 16; ++rr) {
        int mrow = c * 16 + rr;
        float wm = expf(attlog[mrow] - mx) * inv;
        f4 e = __builtin_nontemporal_load((const f4*)(E + (size_t)mrow * HH) + col4);
        acc[0] = fmaf(wm, e[0], acc[0]);
        acc[1] = fmaf(wm, e[1], acc[1]);
        acc[2] = fmaf(wm, e[2], acc[2]);
        acc[3] = fmaf(wm, e[3], acc[3]);
    }
    ((f4*)(part + (size_t)c * HH))[col4] = acc;

    if (q == 0 && t < 16) {
        int mrow = c * 16 + t;
        atw[mrow] = expf(attlog[mrow] - mx) * inv;
    }
}

// deterministic reduce of 128 partial rows -> atap (part is L2-resident)
__global__ void k_red(const float* __restrict__ part, float* __restrict__ atap) {
    int j = blockIdx.x * 256 + threadIdx.x;
    float s = 0.f;
#pragma unroll 8
    for (int c = 0; c < 128; ++c) s += part[(size_t)c * HH + j];
    atap[j] = s;
}

// x = relu(atc_W @ [emb | atap] + atc_b), block per row; atc_W stream-once
__global__ void k_atc(const float* __restrict__ atc_W, const float* __restrict__ atc_b,
                      const float* __restrict__ emb_W, const int* __restrict__ idx,
                      const float* __restrict__ atap, float* __restrict__ x) {
    int r = blockIdx.x;
    const float* emb = emb_W + (size_t)idx[0] * HH;
    const float* Wr = atc_W + (size_t)r * (2 * HH);
    float acc = dot_row<4, true>((const f4*)Wr, (const f4*)emb)
              + dot_row<4, true>((const f4*)(Wr + HH), (const f4*)atap);
    float tot = block_sum(acc);
    if (threadIdx.x == 0) x[r] = fmaxf(tot + atc_b[r], 0.f);
}

// fused GRU: block r computes all 6 row-dots as SEQUENTIAL streaming passes
// (R3-proven: low VGPR pressure, one stream at a time), then gate math.
// W_ih is nt (stream-once); W_hh uses normal loads (L3-residency candidate).
__global__ void k_gru(const float* __restrict__ W_ih, const float* __restrict__ b_ih,
                      const float* __restrict__ W_hh, const float* __restrict__ b_hh,
                      const float* __restrict__ x, const float* __restrict__ h,
                      float* __restrict__ h_new) {
    __shared__ float red[6][4];
    int r = blockIdx.x;
    int t = threadIdx.x, wid = t >> 6, lane = t & 63;
    const f4* xv = (const f4*)x;
    const f4* hv = (const f4*)h;
    float a[6];
    a[0] = dot_row<4, true >((const f4*)(W_ih + (size_t)r * HH), xv);
    a[1] = dot_row<4, true >((const f4*)(W_ih + (size_t)(HH + r) * HH), xv);
    a[2] = dot_row<4, true >((const f4*)(W_ih + (size_t)(2 * HH + r) * HH), xv);
    a[3] = dot_row<4, false>((const f4*)(W_hh + (size_t)r * HH), hv);
    a[4] = dot_row<4, false>((const f4*)(W_hh + (size_t)(HH + r) * HH), hv);
    a[5] = dot_row<4, false>((const f4*)(W_hh + (size_t)(2 * HH + r) * HH), hv);
#pragma unroll
    for (int k = 0; k < 6; ++k) {
        float s = wave_sum(a[k]);
        if (lane == 0) red[k][wid] = s;
    }
    __syncthreads();
    if (t == 0) {
        float g[6];
#pragma unroll
        for (int k = 0; k < 6; ++k) g[k] = red[k][0] + red[k][1] + red[k][2] + red[k][3];
        float i_r = g[0] + b_ih[r];
        float i_z = g[1] + b_ih[HH + r];
        float i_n = g[2] + b_ih[2 * HH + r];
        float h_r = g[3] + b_hh[r];
        float h_z = g[4] + b_hh[HH + r];
        float h_n = g[5] + b_hh[2 * HH + r];
        float rg = 1.f / (1.f + expf(-(i_r + h_r)));
        float z  = 1.f / (1.f + expf(-(i_z + h_z)));
        float n  = tanhf(i_n + rg * h_n);
        h_new[r] = (1.f - z) * n + z * h[r];
    }
}

// out logits: block per row, L=4096; out_W stream-once
__global__ void k_out(const float* __restrict__ W, const float* __restrict__ xv,
                      const float* __restrict__ b, float* __restrict__ y) {
    int r = blockIdx.x;
    float acc = dot_row<4, true>((const f4*)(W + (size_t)r * HH), (const f4*)xv);
    float tot = block_sum(acc);
    if (threadIdx.x == 0) y[r] = tot + b[r];
}

// log_softmax over 4096: 16 blocks, each redundantly computes the stats
// (identical order -> identical lse) and writes its own 256-col slice.
__global__ void k_lsm(const float* __restrict__ l, float* __restrict__ out) {
    __shared__ float red[4];
    __shared__ float bval;
    int t = threadIdx.x;
    float v[16];
    float m = -INFINITY;
#pragma unroll
    for (int j = 0; j < 16; ++j) { v[j] = l[t + 256 * j]; m = fmaxf(m, v[j]); }
    m = wave_max(m);
    if ((t & 63) == 0) red[t >> 6] = m;
    __syncthreads();
    if (t == 0) bval = fmaxf(fmaxf(red[0], red[1]), fmaxf(red[2], red[3]));
    __syncthreads();
    float mx = bval;
    float s = 0.f;
#pragma unroll
    for (int j = 0; j < 16; ++j) s += expf(v[j] - mx);
    s = wave_sum(s);
    __syncthreads();
    if ((t & 63) == 0) red[t >> 6] = s;
    __syncthreads();
    if (t == 0) bval = red[0] + red[1] + red[2] + red[3];
    __syncthreads();
    float lse = mx + logf(bval);
    // thread t's value v[j] sits at index t + 256*j; block b owns j == b
    out[blockIdx.x * 256 + t] = v[blockIdx.x] - lse;
}

extern "C" void kernel_launch(void* const* d_in, const int* in_sizes, int n_in,
                              void* d_out, int out_size, void* d_ws, size_t ws_size,
                              hipStream_t stream) {
    const int*   idx     = (const int*)  d_in[0];
    const float* hidden  = (const float*)d_in[1];
    // d_in[2] (encoder_output) unused by the forward pass
    const float* enc     = (const float*)d_in[3];
    const float* emb_W   = (const float*)d_in[4];
    const float* att_W   = (const float*)d_in[5];
    const float* att_b   = (const float*)d_in[6];
    const float* atc_W   = (const float*)d_in[7];
    const float* atc_b   = (const float*)d_in[8];
    const float* W_ih    = (const float*)d_in[9];
    const float* W_hh    = (const float*)d_in[10];
    const float* b_ih    = (const float*)d_in[11];
    const float* b_hh    = (const float*)d_in[12];
    const float* out_W   = (const float*)d_in[13];
    const float* out_b   = (const float*)d_in[14];

    float* out    = (float*)d_out;        // [0, 4096)    log_softmax
    float* h_new  = out + OO;             // [4096, 8192) new hidden
    float* atw    = out + OO + HH;        // [8192,10240) attention weights

    float* ws         = (float*)d_ws;
    float* attlog     = ws;               // 2048
    float* atap       = ws + 2048;        // 4096
    float* x          = ws + 6144;        // 4096
    float* outlog     = ws + 10240;       // 4096
    float* part       = ws + 14336;       // 128*4096

    // 1. att logits (block per row)
    k_att<<<MAXLEN, 256, 0, stream>>>(att_W, att_b, emb_W, idx, hidden, attlog);
    // 2. fused softmax + weighted partial column-sums (also writes atw output)
    k_smpart<<<512, 256, 0, stream>>>(attlog, enc, part, atw);
    // 3. deterministic reduce -> atap
    k_red<<<16, 256, 0, stream>>>(part, atap);
    // 4. x = relu(atc_W @ [emb|atap] + atc_b) (block per row)
    k_atc<<<HH, 256, 0, stream>>>(atc_W, atc_b, emb_W, idx, atap, x);
    // 5. fused GRU (sequential streaming passes) -> h_new output
    k_gru<<<HH, 256, 0, stream>>>(W_ih, b_ih, W_hh, b_hh, x, hidden, h_new);
    // 6. out logits (block per row)
    k_out<<<HH, 256, 0, stream>>>(out_W, h_new, out_b, outlog);
    // 7. log_softmax -> out (16 blocks, redundant stats)
    k_lsm<<<16, 256, 0, stream>>>(outlog, out);
}

// Round 6
// 129.181 us; speedup vs baseline: 1.1997x; 1.0069x over previous
//
#include <hip/hip_runtime.h>
#include <math.h>

#define HH 4096
#define OO 4096
#define MAXLEN 2048

typedef float f4 __attribute__((ext_vector_type(4)));

__device__ inline float wave_sum(float v) {
#pragma unroll
    for (int off = 32; off; off >>= 1) v += __shfl_down(v, off, 64);
    return v;
}
__device__ inline float wave_max(float v) {
#pragma unroll
    for (int off = 32; off; off >>= 1) v = fmaxf(v, __shfl_down(v, off, 64));
    return v;
}

// sum 256 per-thread partials; result valid in all threads
__device__ inline float block_sum(float acc) {
    __shared__ float red[4];
    acc = wave_sum(acc);
    int t = threadIdx.x;
    if ((t & 63) == 0) red[t >> 6] = acc;
    __syncthreads();
    return red[0] + red[1] + red[2] + red[3];
}

// per-thread partial dot over 1024*NV floats; 256 threads/block.
// NT: non-temporal (stream-once) hint on the W side only.
template <int NV, bool NT>
__device__ inline float dot_row(const f4* __restrict__ W4, const f4* __restrict__ x4) {
    int t = threadIdx.x;
    float acc = 0.f;
#pragma unroll
    for (int j = 0; j < NV; ++j) {
        f4 w = NT ? __builtin_nontemporal_load(W4 + t + 256 * j) : W4[t + 256 * j];
        f4 v = x4[t + 256 * j];
        acc = fmaf(w[0], v[0], acc);
        acc = fmaf(w[1], v[1], acc);
        acc = fmaf(w[2], v[2], acc);
        acc = fmaf(w[3], v[3], acc);
    }
    return acc;
}

// fused first stage: blocks 0..2047 -> attention logits (att_W nt, L=8192)
//                    blocks 2048..14335 -> gh[r] = W_hh[r,:]·h + b_hh[r] (non-nt)
__global__ void k_stage1(const float* __restrict__ att_W, const float* __restrict__ att_b,
                         const float* __restrict__ emb_W, const int* __restrict__ idx,
                         const float* __restrict__ hidden,
                         const float* __restrict__ W_hh, const float* __restrict__ b_hh,
                         float* __restrict__ attlog, float* __restrict__ gh) {
    int blk = blockIdx.x;
    if (blk < MAXLEN) {
        const float* emb = emb_W + (size_t)idx[0] * HH;
        const float* Wr = att_W + (size_t)blk * (2 * HH);
        float acc = dot_row<4, true>((const f4*)Wr, (const f4*)emb)
                  + dot_row<4, true>((const f4*)(Wr + HH), (const f4*)hidden);
        float tot = block_sum(acc);
        if (threadIdx.x == 0) attlog[blk] = tot + att_b[blk];
    } else {
        int r = blk - MAXLEN;
        float acc = dot_row<4, false>((const f4*)(W_hh + (size_t)r * HH), (const f4*)hidden);
        float tot = block_sum(acc);
        if (threadIdx.x == 0) gh[r] = tot + b_hh[r];
    }
}

// fused softmax + weighted partial column-sums.
// 512 blocks = 128 row-chunks (16 rows) x 4 col-quarters. Each block
// redundantly computes softmax stats from attlog (8KB, L2/L3-resident).
// q==0 blocks also write atw (the third output). enc is stream-once (nt).
__global__ void k_smpart(const float* __restrict__ attlog, const float* __restrict__ E,
                         float* __restrict__ part, float* __restrict__ atw) {
    __shared__ float red[4];
    __shared__ float s_mx, s_sum;
    int t = threadIdx.x;
    int q = blockIdx.x & 3;
    int c = blockIdx.x >> 2;              // 0..127

    float v[8];
    float m = -INFINITY;
#pragma unroll
    for (int j = 0; j < 8; ++j) { v[j] = attlog[t + 256 * j]; m = fmaxf(m, v[j]); }
    m = wave_max(m);
    if ((t & 63) == 0) red[t >> 6] = m;
    __syncthreads();
    if (t == 0) s_mx = fmaxf(fmaxf(red[0], red[1]), fmaxf(red[2], red[3]));
    __syncthreads();
    float mx = s_mx;
    float s = 0.f;
#pragma unroll
    for (int j = 0; j < 8; ++j) s += expf(v[j] - mx);
    s = wave_sum(s);
    __syncthreads();
    if ((t & 63) == 0) red[t >> 6] = s;
    __syncthreads();
    if (t == 0) s_sum = red[0] + red[1] + red[2] + red[3];
    __syncthreads();
    float inv = 1.0f / s_sum;

    int col4 = q * 256 + t;
    f4 acc = {0.f, 0.f, 0.f, 0.f};
#pragma unroll 8
    for (int rr = 0; rr < 16; ++rr) {
        int mrow = c * 16 + rr;
        float wm = expf(attlog[mrow] - mx) * inv;
        f4 e = __builtin_nontemporal_load((const f4*)(E + (size_t)mrow * HH) + col4);
        acc[0] = fmaf(wm, e[0], acc[0]);
        acc[1] = fmaf(wm, e[1], acc[1]);
        acc[2] = fmaf(wm, e[2], acc[2]);
        acc[3] = fmaf(wm, e[3], acc[3]);
    }
    ((f4*)(part + (size_t)c * HH))[col4] = acc;

    if (q == 0 && t < 16) {
        int mrow = c * 16 + t;
        atw[mrow] = expf(attlog[mrow] - mx) * inv;
    }
}

// deterministic reduce of 128 partial rows -> atap (part is L2-resident)
__global__ void k_red(const float* __restrict__ part, float* __restrict__ atap) {
    int j = blockIdx.x * 256 + threadIdx.x;
    float s = 0.f;
#pragma unroll 8
    for (int c = 0; c < 128; ++c) s += part[(size_t)c * HH + j];
    atap[j] = s;
}

// x = relu(atc_W @ [emb | atap] + atc_b), block per row; atc_W stream-once
__global__ void k_atc(const float* __restrict__ atc_W, const float* __restrict__ atc_b,
                      const float* __restrict__ emb_W, const int* __restrict__ idx,
                      const float* __restrict__ atap, float* __restrict__ x) {
    int r = blockIdx.x;
    const float* emb = emb_W + (size_t)idx[0] * HH;
    const float* Wr = atc_W + (size_t)r * (2 * HH);
    float acc = dot_row<4, true>((const f4*)Wr, (const f4*)emb)
              + dot_row<4, true>((const f4*)(Wr + HH), (const f4*)atap);
    float tot = block_sum(acc);
    if (threadIdx.x == 0) x[r] = fmaxf(tot + atc_b[r], 0.f);
}

// gi + gate math: block r computes 3 W_ih row-dots vs x (nt), combines with
// precomputed gh (already includes b_hh) -> h_new[r]. 48KB streamed per block.
__global__ void k_gig(const float* __restrict__ W_ih, const float* __restrict__ b_ih,
                      const float* __restrict__ x, const float* __restrict__ gh,
                      const float* __restrict__ h, float* __restrict__ h_new) {
    __shared__ float red[3][4];
    int r = blockIdx.x;
    int t = threadIdx.x, wid = t >> 6, lane = t & 63;
    const f4* xv = (const f4*)x;
    float a[3];
    a[0] = dot_row<4, true>((const f4*)(W_ih + (size_t)r * HH), xv);
    a[1] = dot_row<4, true>((const f4*)(W_ih + (size_t)(HH + r) * HH), xv);
    a[2] = dot_row<4, true>((const f4*)(W_ih + (size_t)(2 * HH + r) * HH), xv);
#pragma unroll
    for (int k = 0; k < 3; ++k) {
        float s = wave_sum(a[k]);
        if (lane == 0) red[k][wid] = s;
    }
    __syncthreads();
    if (t == 0) {
        float i_r = red[0][0] + red[0][1] + red[0][2] + red[0][3] + b_ih[r];
        float i_z = red[1][0] + red[1][1] + red[1][2] + red[1][3] + b_ih[HH + r];
        float i_n = red[2][0] + red[2][1] + red[2][2] + red[2][3] + b_ih[2 * HH + r];
        float h_r = gh[r];
        float h_z = gh[HH + r];
        float h_n = gh[2 * HH + r];
        float rg = 1.f / (1.f + expf(-(i_r + h_r)));
        float z  = 1.f / (1.f + expf(-(i_z + h_z)));
        float n  = tanhf(i_n + rg * h_n);
        h_new[r] = (1.f - z) * n + z * h[r];
    }
}

// out logits: block per row, L=4096; out_W stream-once
__global__ void k_out(const float* __restrict__ W, const float* __restrict__ xv,
                      const float* __restrict__ b, float* __restrict__ y) {
    int r = blockIdx.x;
    float acc = dot_row<4, true>((const f4*)(W + (size_t)r * HH), (const f4*)xv);
    float tot = block_sum(acc);
    if (threadIdx.x == 0) y[r] = tot + b[r];
}

// log_softmax over 4096: 16 blocks, each redundantly computes the stats
// (identical order -> identical lse) and writes its own 256-col slice.
__global__ void k_lsm(const float* __restrict__ l, float* __restrict__ out) {
    __shared__ float red[4];
    __shared__ float bval;
    int t = threadIdx.x;
    float v[16];
    float m = -INFINITY;
#pragma unroll
    for (int j = 0; j < 16; ++j) { v[j] = l[t + 256 * j]; m = fmaxf(m, v[j]); }
    m = wave_max(m);
    if ((t & 63) == 0) red[t >> 6] = m;
    __syncthreads();
    if (t == 0) bval = fmaxf(fmaxf(red[0], red[1]), fmaxf(red[2], red[3]));
    __syncthreads();
    float mx = bval;
    float s = 0.f;
#pragma unroll
    for (int j = 0; j < 16; ++j) s += expf(v[j] - mx);
    s = wave_sum(s);
    __syncthreads();
    if ((t & 63) == 0) red[t >> 6] = s;
    __syncthreads();
    if (t == 0) bval = red[0] + red[1] + red[2] + red[3];
    __syncthreads();
    float lse = mx + logf(bval);
    // thread t's value v[j] sits at index t + 256*j; block b owns j == b
    out[blockIdx.x * 256 + t] = v[blockIdx.x] - lse;
}

extern "C" void kernel_launch(void* const* d_in, const int* in_sizes, int n_in,
                              void* d_out, int out_size, void* d_ws, size_t ws_size,
                              hipStream_t stream) {
    const int*   idx     = (const int*)  d_in[0];
    const float* hidden  = (const float*)d_in[1];
    // d_in[2] (encoder_output) unused by the forward pass
    const float* enc     = (const float*)d_in[3];
    const float* emb_W   = (const float*)d_in[4];
    const float* att_W   = (const float*)d_in[5];
    const float* att_b   = (const float*)d_in[6];
    const float* atc_W   = (const float*)d_in[7];
    const float* atc_b   = (const float*)d_in[8];
    const float* W_ih    = (const float*)d_in[9];
    const float* W_hh    = (const float*)d_in[10];
    const float* b_ih    = (const float*)d_in[11];
    const float* b_hh    = (const float*)d_in[12];
    const float* out_W   = (const float*)d_in[13];
    const float* out_b   = (const float*)d_in[14];

    float* out    = (float*)d_out;        // [0, 4096)    log_softmax
    float* h_new  = out + OO;             // [4096, 8192) new hidden
    float* atw    = out + OO + HH;        // [8192,10240) attention weights

    float* ws         = (float*)d_ws;
    float* attlog     = ws;               // 2048
    float* atap       = ws + 2048;        // 4096
    float* x          = ws + 6144;        // 4096
    float* outlog     = ws + 10240;       // 4096
    float* gh         = ws + 14336;       // 12288
    float* part       = ws + 26624;       // 128*4096

    // 1. att logits + gh = W_hh@hidden + b_hh (fused, 14336 blocks)
    k_stage1<<<MAXLEN + 3 * HH, 256, 0, stream>>>(att_W, att_b, emb_W, idx, hidden,
                                                  W_hh, b_hh, attlog, gh);
    // 2. fused softmax + weighted partial column-sums (also writes atw output)
    k_smpart<<<512, 256, 0, stream>>>(attlog, enc, part, atw);
    // 3. deterministic reduce -> atap
    k_red<<<16, 256, 0, stream>>>(part, atap);
    // 4. x = relu(atc_W @ [emb|atap] + atc_b) (block per row)
    k_atc<<<HH, 256, 0, stream>>>(atc_W, atc_b, emb_W, idx, atap, x);
    // 5. gi + gate math -> h_new output
    k_gig<<<HH, 256, 0, stream>>>(W_ih, b_ih, x, gh, hidden, h_new);
    // 6. out logits (block per row)
    k_out<<<HH, 256, 0, stream>>>(out_W, h_new, out_b, outlog);
    // 7. log_softmax -> out (16 blocks, redundant stats)
    k_lsm<<<16, 256, 0, stream>>>(outlog, out);
}